// Round 7
// baseline (255.767 us; speedup 1.0000x reference)
//
#include <hip/hip_runtime.h>
#include <hip/hip_bf16.h>

// Problem constants
#define C_   32
#define S_   20
#define V_   8000     // 20^3
#define K3_  125
#define OC_  375      // 3*K3
#define NP_  384      // padded N
#define KK_  4000     // 32*125

// Workspace layout (float offsets). Peak 2.704M floats = 10.82 MB.
#define WS_ATTN1T 0                        // fp32 [v][c]          256000
#define WS_XTB    256000                   // bf16 [v][c]          128000 fl
#define WS_WDWT   384000                   // fp32 [k][c]            4000
#define WS_WSPT   388000                   // fp32 [k][c]           10976
#define WS_WPWT   398976                   // fp32 [c][o]            1024
#define WS_OFFB   400000                   // bf16 [v][384]       1536000 fl
#define WS_BPREP  1936000                  // bf16 [tap][384][32] 768000 fl
#define WS_ATTN2T 1936000                  //   dead after gemm -> fp32 [v][c]

typedef __attribute__((ext_vector_type(8))) short bf16x8;
typedef __attribute__((ext_vector_type(4))) float f32x4;

static __device__ __forceinline__ unsigned short f2bf(float f) {
    union { float f; unsigned u; } v; v.f = f;
    unsigned r = v.u + 0x7FFFu + ((v.u >> 16) & 1u);   // RTNE
    return (unsigned short)(r >> 16);
}
static __device__ __forceinline__ float bf2f(unsigned short b) {
    union { unsigned u; float f; } v; v.u = ((unsigned)b) << 16; return v.f;
}
static __device__ __forceinline__ float asf(unsigned u) {
    union { unsigned u; float f; } v; v.u = u; return v.f;
}

// ---------------------------------------------------------------------------
// Transposes: xtb[v][c] bf16; wdwT[k][c]; wspT[k][c]; wpwT[c][o] (fp32).
// ---------------------------------------------------------------------------
__global__ __launch_bounds__(256) void transpose_kernel(
    const float* __restrict__ x,
    const float* __restrict__ w_dw,
    const float* __restrict__ w_sp,
    const float* __restrict__ w_pw,
    unsigned short* __restrict__ xtb,
    float* __restrict__ wdwT,
    float* __restrict__ wspT,
    float* __restrict__ wpwT)
{
    int i = blockIdx.x * 256 + threadIdx.x;
    if (i < 256000) {
        int v = i >> 5, c = i & 31;
        xtb[i] = f2bf(x[c * V_ + v]);
        return;
    }
    int j = i - 256000;
    if (j < 4000)  { wdwT[j] = w_dw[(j & 31) * K3_ + (j >> 5)]; return; }
    j -= 4000;
    if (j < 10976) { wspT[j] = w_sp[(j & 31) * 343 + (j >> 5)]; return; }
    j -= 10976;
    if (j < 1024)  { wpwT[j] = w_pw[(j & 31) * 32 + (j >> 5)]; return; }
}

// ---------------------------------------------------------------------------
// Weight transform: Bfrag[tap][n][c] bf16 (n >= 375 zeroed) — MFMA B-fragment
// order so gemm lanes load B directly from global, fully coalesced.
// ---------------------------------------------------------------------------
__global__ __launch_bounds__(256) void prep_b_kernel(
    const float* __restrict__ w_off, unsigned short* __restrict__ Bfrag)
{
    int idx = blockIdx.x * 256 + threadIdx.x;
    if (idx >= K3_ * NP_ * C_) return;
    int tap = idx / (NP_ * C_);
    int r   = idx % (NP_ * C_);
    int n = r >> 5, c = r & 31;
    float v = (n < OC_) ? w_off[n * KK_ + c * K3_ + tap] : 0.f;
    Bfrag[idx] = f2bf(v);
}

// ---------------------------------------------------------------------------
// Offset conv as implicit-GEMM MFMA: D[8000][384] = A[8000][4000]*B[4000][384].
// Barrier-free, LDS-free: A and B fragments loaded straight from global
// (xtb[v][32] is exactly one tap's K-chunk; Bfrag pre-shaped). Tile 64x64,
// 4 waves 2x2, wave tile 32x32, mfma 16x16x32 bf16. Writes offbT[v][n].
// ---------------------------------------------------------------------------
__global__ __launch_bounds__(256) void gemm_off_kernel(
    const unsigned short* __restrict__ xtb,
    const unsigned short* __restrict__ Bfrag,
    const float* __restrict__ b_off,
    unsigned short* __restrict__ offbT)
{
    const int t    = threadIdx.x;
    const int lane = t & 63;
    const int wave = t >> 6;
    const int wr   = wave >> 1;
    const int wc   = wave & 1;
    const int quad = lane >> 4;
    const int lrow = lane & 15;
    const int M0   = blockIdx.x * 64;
    const int N0   = blockIdx.y * 64;

    // Per-lane A-row coordinates (mi = 0,1)
    const int m0 = M0 + wr * 32 + lrow;
    const int m1 = m0 + 16;
    const int az0 = m0 / 400, rr0 = m0 % 400, ay0 = rr0 / 20, ax0 = rr0 % 20;
    const int az1 = m1 / 400, rr1 = m1 % 400, ay1 = rr1 / 20, ax1 = rr1 % 20;

    // Per-lane B fragment pointers (ni = 0,1); advance 384*32 shorts per tap.
    const unsigned short* bp0 = Bfrag + (size_t)(N0 + wc * 32 + lrow) * 32 + quad * 8;
    const unsigned short* bp1 = bp0 + 16 * 32;

    f32x4 acc[2][2] = {};
    int tap = 0;
    #pragma unroll 1
    for (int kz = 0; kz < 5; ++kz) {
        int zi0 = az0 - 2 + kz, zi1 = az1 - 2 + kz;
        bool zv0 = (unsigned)zi0 < (unsigned)S_;
        bool zv1 = (unsigned)zi1 < (unsigned)S_;
        #pragma unroll 1
        for (int ky = 0; ky < 5; ++ky) {
            int yi0 = ay0 - 2 + ky, yi1 = ay1 - 2 + ky;
            bool zy0 = zv0 & ((unsigned)yi0 < (unsigned)S_);
            bool zy1 = zv1 & ((unsigned)yi1 < (unsigned)S_);
            int pb0 = zi0 * 400 + yi0 * 20 + ax0 - 2;
            int pb1 = zi1 * 400 + yi1 * 20 + ax1 - 2;
            #pragma unroll
            for (int kx = 0; kx < 5; ++kx, ++tap) {
                bool ok0 = zy0 & ((unsigned)(ax0 - 2 + kx) < (unsigned)S_);
                bool ok1 = zy1 & ((unsigned)(ax1 - 2 + kx) < (unsigned)S_);
                int px0 = ok0 ? (pb0 + kx) : 0;
                int px1 = ok1 ? (pb1 + kx) : 0;
                bf16x8 a0 = *(const bf16x8*)(xtb + px0 * 32 + quad * 8);
                bf16x8 a1 = *(const bf16x8*)(xtb + px1 * 32 + quad * 8);
                const unsigned short* bt = (size_t)tap * (NP_ * 32) + (const unsigned short*)0 + 0, *dummy = bt; (void)dummy;
                bf16x8 b0 = *(const bf16x8*)(bp0 + (size_t)tap * (NP_ * 32));
                bf16x8 b1 = *(const bf16x8*)(bp1 + (size_t)tap * (NP_ * 32));
                if (!ok0) a0 = (bf16x8)(short)0;
                if (!ok1) a1 = (bf16x8)(short)0;
                acc[0][0] = __builtin_amdgcn_mfma_f32_16x16x32_bf16(a0, b0, acc[0][0], 0, 0, 0);
                acc[0][1] = __builtin_amdgcn_mfma_f32_16x16x32_bf16(a0, b1, acc[0][1], 0, 0, 0);
                acc[1][0] = __builtin_amdgcn_mfma_f32_16x16x32_bf16(a1, b0, acc[1][0], 0, 0, 0);
                acc[1][1] = __builtin_amdgcn_mfma_f32_16x16x32_bf16(a1, b1, acc[1][1], 0, 0, 0);
            }
        }
    }

    #pragma unroll
    for (int mi = 0; mi < 2; ++mi) {
        #pragma unroll
        for (int ni = 0; ni < 2; ++ni) {
            int n = N0 + wc * 32 + ni * 16 + lrow;
            if (n < OC_) {
                float bias = b_off[n];
                #pragma unroll
                for (int r = 0; r < 4; ++r) {
                    int row = wr * 32 + mi * 16 + quad * 4 + r;
                    offbT[(size_t)(M0 + row) * 384 + n] = f2bf(acc[mi][ni][r] + bias);
                }
            }
        }
    }
}

// ---------------------------------------------------------------------------
// Deformable depthwise sample, two-phase.
// Phase 1: per (voxel, tap) geometry computed ONCE -> 24B in LDS.
// Phase 2: thread=(v,c); 3 broadcast LDS dwords + 8 coalesced gathers + FMAs.
// ---------------------------------------------------------------------------
#define VB 8
__global__ __launch_bounds__(256) void deform_kernel(
    const unsigned short* __restrict__ xtb,
    const float* __restrict__ wdwT,
    const float* __restrict__ b_dw,
    const unsigned short* __restrict__ offbT,
    float* __restrict__ attn1T)
{
    __shared__ unsigned short sw[VB * 128 * 12];   // 24 KB
    const int tid = threadIdx.x;
    const int Vb = blockIdx.x * VB;

    for (int idx = tid; idx < VB * 128; idx += 256) {
        int vl = idx >> 7, tap = idx & 127;
        if (tap < K3_) {
            int v = Vb + vl;
            int z = v / 400, rm = v % 400;
            int y = rm / 20, xx = rm % 20;
            int kz = tap / 25, ky = (tap / 5) % 5, kx = tap % 5;
            const unsigned short* ob = offbT + v * 384 + 3 * tap;
            float pd = (float)(z - 2 + kz) + bf2f(ob[0]);
            float ph = (float)(y - 2 + ky) + bf2f(ob[1]);
            float pw = (float)(xx - 2 + kx) + bf2f(ob[2]);
            float fd0 = floorf(pd), fh0 = floorf(ph), fw0 = floorf(pw);
            float fd = pd - fd0, fh = ph - fh0, fw = pw - fw0;
            int id = (int)fd0, ih = (int)fh0, iw = (int)fw0;
            int d0 = min(max(id, 0), S_ - 1), d1 = min(max(id + 1, 0), S_ - 1);
            int h0 = min(max(ih, 0), S_ - 1), h1 = min(max(ih + 1, 0), S_ - 1);
            int w0 = min(max(iw, 0), S_ - 1), w1 = min(max(iw + 1, 0), S_ - 1);
            float wd0 = ((unsigned)id       < (unsigned)S_) ? 1.f - fd : 0.f;
            float wd1 = ((unsigned)(id + 1) < (unsigned)S_) ? fd       : 0.f;
            float wh0 = ((unsigned)ih       < (unsigned)S_) ? 1.f - fh : 0.f;
            float wh1 = ((unsigned)(ih + 1) < (unsigned)S_) ? fh       : 0.f;
            float ww0 = ((unsigned)iw       < (unsigned)S_) ? 1.f - fw : 0.f;
            float ww1 = ((unsigned)(iw + 1) < (unsigned)S_) ? fw       : 0.f;
            unsigned short* p = &sw[idx * 12];
            p[0] = f2bf(wd0 * wh0); p[1] = f2bf(wd0 * wh1);
            p[2] = f2bf(wd1 * wh0); p[3] = f2bf(wd1 * wh1);
            p[4] = f2bf(ww0);       p[5] = f2bf(ww1);
            p[6] = (unsigned short)(d0 * 400 + h0 * 20);
            p[7] = (unsigned short)(d0 * 400 + h1 * 20);
            p[8] = (unsigned short)(d1 * 400 + h0 * 20);
            p[9] = (unsigned short)(d1 * 400 + h1 * 20);
            p[10] = (unsigned short)w0; p[11] = (unsigned short)w1;
        }
    }
    __syncthreads();

    const int c = tid & 31;
    const int vl = tid >> 5;
    const int v = Vb + vl;
    const unsigned short* xc = xtb + c;
    float acc = 0.f;
    #pragma unroll 2
    for (int tap = 0; tap < K3_; ++tap) {
        const unsigned* pu = (const unsigned*)&sw[(vl * 128 + tap) * 12];
        unsigned u0 = pu[0], u1 = pu[1], u2 = pu[2];
        unsigned u3 = pu[3], u4 = pu[4], u5 = pu[5];
        float wdh00 = asf(u0 << 16), wdh01 = asf(u0 & 0xFFFF0000u);
        float wdh10 = asf(u1 << 16), wdh11 = asf(u1 & 0xFFFF0000u);
        float ww0   = asf(u2 << 16), ww1   = asf(u2 & 0xFFFF0000u);
        int r00 = u3 & 0xFFFFu, r01 = u3 >> 16;
        int r10 = u4 & 0xFFFFu, r11 = u4 >> 16;
        int w0  = u5 & 0xFFFFu, w1  = u5 >> 16;
        float x000 = bf2f(xc[(r00 + w0) * 32]);
        float x001 = bf2f(xc[(r00 + w1) * 32]);
        float x010 = bf2f(xc[(r01 + w0) * 32]);
        float x011 = bf2f(xc[(r01 + w1) * 32]);
        float x100 = bf2f(xc[(r10 + w0) * 32]);
        float x101 = bf2f(xc[(r10 + w1) * 32]);
        float x110 = bf2f(xc[(r11 + w0) * 32]);
        float x111 = bf2f(xc[(r11 + w1) * 32]);
        float s = (x000 * ww0 + x001 * ww1) * wdh00
                + (x010 * ww0 + x011 * ww1) * wdh01
                + (x100 * ww0 + x101 * ww1) * wdh10
                + (x110 * ww0 + x111 * ww1) * wdh11;
        acc += wdwT[tap * 32 + c] * s;
    }
    attn1T[v * 32 + c] = acc + b_dw[c];
}

// ---------------------------------------------------------------------------
// Depthwise 7^3 conv, dilation 3, pad 9, channel-last, coalesced.
// ---------------------------------------------------------------------------
__global__ __launch_bounds__(256) void spatial_kernel(
    const float* __restrict__ wspT,
    const float* __restrict__ b_sp,
    const float* __restrict__ attn1T,
    float* __restrict__ attn2T)
{
    int t = threadIdx.x;
    int c = t & 31;
    int v = blockIdx.x * 8 + (t >> 5);
    int z = v / 400, rm = v % 400;
    int y = rm / 20, xx = rm % 20;

    float acc = 0.f;
    #pragma unroll 1
    for (int kz = 0; kz < 7; ++kz) {
        int zi = z - 9 + 3 * kz;
        bool zv = (unsigned)zi < (unsigned)S_;
        int zc2 = min(max(zi, 0), S_ - 1);
        #pragma unroll 1
        for (int ky = 0; ky < 7; ++ky) {
            int yi = y - 9 + 3 * ky;
            bool yv = (unsigned)yi < (unsigned)S_;
            int yc2 = min(max(yi, 0), S_ - 1);
            int abase = (zc2 * 400 + yc2 * 20) * 32 + c;
            int wbase = (kz * 49 + ky * 7) * 32 + c;
            #pragma unroll
            for (int kx = 0; kx < 7; ++kx) {
                int xi = xx - 9 + 3 * kx;
                bool xv = (unsigned)xi < (unsigned)S_;
                int xc2 = min(max(xi, 0), S_ - 1);
                float a = attn1T[abase + xc2 * 32];
                float w = wspT[wbase + kx * 32];
                acc += (zv && yv && xv) ? a * w : 0.f;
            }
        }
    }
    attn2T[v * 32 + c] = acc + b_sp[c];
}

// ---------------------------------------------------------------------------
// Pointwise 32x32 + bias, gate: out[o][v] = x[o][v] * attn.
// ---------------------------------------------------------------------------
__global__ __launch_bounds__(256) void pw_kernel(
    const float* __restrict__ x,
    const float* __restrict__ wpwT,
    const float* __restrict__ b_pw,
    const float* __restrict__ attn2T,
    float* __restrict__ out)
{
    int t = threadIdx.x;
    int o = t & 31;
    int v = blockIdx.x * 8 + (t >> 5);
    float acc = b_pw[o];
    #pragma unroll
    for (int c = 0; c < C_; ++c)
        acc += wpwT[c * 32 + o] * attn2T[v * 32 + c];
    out[o * V_ + v] = x[o * V_ + v] * acc;
}

// ---------------------------------------------------------------------------
extern "C" void kernel_launch(void* const* d_in, const int* in_sizes, int n_in,
                              void* d_out, int out_size, void* d_ws, size_t ws_size,
                              hipStream_t stream)
{
    const float* x     = (const float*)d_in[0];
    const float* w_off = (const float*)d_in[1];
    const float* b_off = (const float*)d_in[2];
    const float* w_dw  = (const float*)d_in[3];
    const float* b_dw  = (const float*)d_in[4];
    const float* w_sp  = (const float*)d_in[5];
    const float* b_sp  = (const float*)d_in[6];
    const float* w_pw  = (const float*)d_in[7];
    const float* b_pw  = (const float*)d_in[8];
    float* ws = (float*)d_ws;
    float* out = (float*)d_out;

    unsigned short* xtb   = (unsigned short*)(ws + WS_XTB);
    unsigned short* offbT = (unsigned short*)(ws + WS_OFFB);
    unsigned short* Bfrag = (unsigned short*)(ws + WS_BPREP);

    hipLaunchKernelGGL(transpose_kernel, dim3((272000 + 255) / 256), dim3(256), 0, stream,
                       x, w_dw, w_sp, w_pw, xtb,
                       ws + WS_WDWT, ws + WS_WSPT, ws + WS_WPWT);

    hipLaunchKernelGGL(prep_b_kernel, dim3((K3_ * NP_ * C_ + 255) / 256), dim3(256), 0, stream,
                       w_off, Bfrag);

    hipLaunchKernelGGL(gemm_off_kernel, dim3(125, 6), dim3(256), 0, stream,
                       xtb, Bfrag, b_off, offbT);

    hipLaunchKernelGGL(deform_kernel, dim3(1000), dim3(256), 0, stream,
                       xtb, ws + WS_WDWT, b_dw, offbT, ws + WS_ATTN1T);

    hipLaunchKernelGGL(spatial_kernel, dim3(1000), dim3(256), 0, stream,
                       ws + WS_WSPT, b_sp, ws + WS_ATTN1T, ws + WS_ATTN2T);

    hipLaunchKernelGGL(pw_kernel, dim3(1000), dim3(256), 0, stream,
                       x, ws + WS_WPWT, b_pw, ws + WS_ATTN2T, out);
}

// Round 8
// 235.977 us; speedup vs baseline: 1.0839x; 1.0839x over previous
//
#include <hip/hip_runtime.h>
#include <hip/hip_bf16.h>

// Problem constants
#define C_   32
#define S_   20
#define V_   8000     // 20^3
#define K3_  125
#define OC_  375      // 3*K3
#define NP_  384      // padded N
#define KK_  4000     // 32*125

// Workspace layout (float offsets). Peak ~2.704M floats = 10.82 MB.
// xtb grew by one zero row (row 8000) -> +16 floats, everything after shifted.
#define WS_ATTN1T 0                        // fp32 [v][c]          256000
#define WS_XTB    256000                   // bf16 [8001][32]      128016 fl
#define WS_WDWT   384016                   // fp32 [k][c]            4000
#define WS_WSPT   388016                   // fp32 [k][c]           10976
#define WS_WPWT   398992                   // fp32 [c][o]            1024
#define WS_OFFB   400016                   // bf16 [v][384]       1536000 fl
#define WS_BPREP  1936016                  // bf16 [tap][4][384][8] 768000 fl
#define WS_ATTN2T 1936016                  //   dead after gemm -> fp32 [v][c]

typedef __attribute__((ext_vector_type(8))) short bf16x8;
typedef __attribute__((ext_vector_type(4))) float f32x4;

static __device__ __forceinline__ unsigned short f2bf(float f) {
    union { float f; unsigned u; } v; v.f = f;
    unsigned r = v.u + 0x7FFFu + ((v.u >> 16) & 1u);   // RTNE
    return (unsigned short)(r >> 16);
}
static __device__ __forceinline__ float bf2f(unsigned short b) {
    union { unsigned u; float f; } v; v.u = ((unsigned)b) << 16; return v.f;
}
static __device__ __forceinline__ float asf(unsigned u) {
    union { unsigned u; float f; } v; v.u = u; return v.f;
}

// ---------------------------------------------------------------------------
// Transposes: xtb[v][c] bf16 (+ zero row 8000); wdwT/wspT[k][c]; wpwT[c][o].
// ---------------------------------------------------------------------------
__global__ __launch_bounds__(256) void transpose_kernel(
    const float* __restrict__ x,
    const float* __restrict__ w_dw,
    const float* __restrict__ w_sp,
    const float* __restrict__ w_pw,
    unsigned short* __restrict__ xtb,
    float* __restrict__ wdwT,
    float* __restrict__ wspT,
    float* __restrict__ wpwT)
{
    int i = blockIdx.x * 256 + threadIdx.x;
    if (i < 256032) {
        int v = i >> 5, c = i & 31;
        xtb[i] = (v < V_) ? f2bf(x[c * V_ + v]) : (unsigned short)0;
        return;
    }
    int j = i - 256032;
    if (j < 4000)  { wdwT[j] = w_dw[(j & 31) * K3_ + (j >> 5)]; return; }
    j -= 4000;
    if (j < 10976) { wspT[j] = w_sp[(j & 31) * 343 + (j >> 5)]; return; }
    j -= 10976;
    if (j < 1024)  { wpwT[j] = w_pw[(j & 31) * 32 + (j >> 5)]; return; }
}

// ---------------------------------------------------------------------------
// Weight transform: B2[tap][q][n][8] bf16 (n >= 375 zeroed), element =
// w_off[n][c=q*8+j][tap]. Makes every gemm B-fragment load contiguous.
// ---------------------------------------------------------------------------
__global__ __launch_bounds__(256) void prep_b_kernel(
    const float* __restrict__ w_off, unsigned short* __restrict__ B2)
{
    int idx = blockIdx.x * 256 + threadIdx.x;
    if (idx >= K3_ * NP_ * C_) return;
    int tap = idx / 12288;
    int r   = idx % 12288;
    int q  = r / 3072;
    int r2 = r % 3072;
    int n = r2 >> 3, j = r2 & 7;
    int c = q * 8 + j;
    float v = (n < OC_) ? w_off[n * KK_ + c * K3_ + tap] : 0.f;
    B2[idx] = f2bf(v);
}

// ---------------------------------------------------------------------------
// Offset conv as implicit-GEMM MFMA: D[8000][384] = A[8000][4000]*B[4000][384].
// Barrier-free + LDS-free, 4-tap rotating register prefetch (16 loads in
// flight). A loads redirect OOB taps to zero row 8000 (no value masking ->
// loads stay pure, compiler keeps vmcnt deep). Tile 64x64, 4 waves 2x2,
// wave tile 32x32, mfma 16x16x32 bf16. Writes offbT[v][n] (+bias).
// ---------------------------------------------------------------------------
__global__ __launch_bounds__(256) void gemm_off_kernel(
    const unsigned short* __restrict__ xtb,
    const unsigned short* __restrict__ B2,
    const float* __restrict__ b_off,
    unsigned short* __restrict__ offbT)
{
    const int t    = threadIdx.x;
    const int lane = t & 63;
    const int wave = t >> 6;
    const int wr   = wave >> 1;
    const int wc   = wave & 1;
    const int quad = lane >> 4;
    const int lrow = lane & 15;
    const int M0   = blockIdx.x * 64;
    const int N0   = blockIdx.y * 64;

    const int m0 = M0 + wr * 32 + lrow;
    const int m1 = m0 + 16;
    const int az0 = m0 / 400, rr0 = m0 % 400, ay0 = rr0 / 20, ax0 = rr0 % 20;
    const int az1 = m1 / 400, rr1 = m1 % 400, ay1 = rr1 / 20, ax1 = rr1 % 20;

    // B fragment pointers into B2[tap][q][n][8]; +12288 shorts per tap.
    const unsigned short* bp0 = B2 + ((size_t)quad * NP_ + (N0 + wc * 32 + lrow)) * 8;
    const unsigned short* bp1 = bp0 + 16 * 8;
    const unsigned short* ap  = xtb + quad * 8;

    bf16x8 a0b[4], a1b[4], b0b[4], b1b[4];

    auto loadtap = [&](int tap, int slot) {
        int tc = min(tap, K3_ - 1);
        int kz = tc / 25, r = tc % 25, ky = r / 5, kx = r % 5;
        int zi0 = az0 - 2 + kz, yi0 = ay0 - 2 + ky, xi0 = ax0 - 2 + kx;
        int zi1 = az1 - 2 + kz, yi1 = ay1 - 2 + ky, xi1 = ax1 - 2 + kx;
        bool ok0 = ((unsigned)zi0 < (unsigned)S_) & ((unsigned)yi0 < (unsigned)S_)
                 & ((unsigned)xi0 < (unsigned)S_);
        bool ok1 = ((unsigned)zi1 < (unsigned)S_) & ((unsigned)yi1 < (unsigned)S_)
                 & ((unsigned)xi1 < (unsigned)S_);
        int px0 = ok0 ? (zi0 * 400 + yi0 * 20 + xi0) : V_;   // row 8000 = zeros
        int px1 = ok1 ? (zi1 * 400 + yi1 * 20 + xi1) : V_;
        a0b[slot] = *(const bf16x8*)(ap + px0 * 32);
        a1b[slot] = *(const bf16x8*)(ap + px1 * 32);
        b0b[slot] = *(const bf16x8*)(bp0 + (size_t)tc * 12288);
        b1b[slot] = *(const bf16x8*)(bp1 + (size_t)tc * 12288);
    };

    #pragma unroll
    for (int s = 0; s < 4; ++s) loadtap(s, s);

    f32x4 acc[2][2] = {};
    #pragma unroll 1
    for (int tb = 0; tb < 124; tb += 4) {
        #pragma unroll
        for (int u = 0; u < 4; ++u) {
            bf16x8 ca0 = a0b[u], ca1 = a1b[u], cb0 = b0b[u], cb1 = b1b[u];
            loadtap(tb + 4 + u, u);
            acc[0][0] = __builtin_amdgcn_mfma_f32_16x16x32_bf16(ca0, cb0, acc[0][0], 0, 0, 0);
            acc[0][1] = __builtin_amdgcn_mfma_f32_16x16x32_bf16(ca0, cb1, acc[0][1], 0, 0, 0);
            acc[1][0] = __builtin_amdgcn_mfma_f32_16x16x32_bf16(ca1, cb0, acc[1][0], 0, 0, 0);
            acc[1][1] = __builtin_amdgcn_mfma_f32_16x16x32_bf16(ca1, cb1, acc[1][1], 0, 0, 0);
        }
    }
    {   // tail: tap 124 sits in slot 0
        bf16x8 ca0 = a0b[0], ca1 = a1b[0], cb0 = b0b[0], cb1 = b1b[0];
        acc[0][0] = __builtin_amdgcn_mfma_f32_16x16x32_bf16(ca0, cb0, acc[0][0], 0, 0, 0);
        acc[0][1] = __builtin_amdgcn_mfma_f32_16x16x32_bf16(ca0, cb1, acc[0][1], 0, 0, 0);
        acc[1][0] = __builtin_amdgcn_mfma_f32_16x16x32_bf16(ca1, cb0, acc[1][0], 0, 0, 0);
        acc[1][1] = __builtin_amdgcn_mfma_f32_16x16x32_bf16(ca1, cb1, acc[1][1], 0, 0, 0);
    }

    #pragma unroll
    for (int mi = 0; mi < 2; ++mi) {
        #pragma unroll
        for (int ni = 0; ni < 2; ++ni) {
            int n = N0 + wc * 32 + ni * 16 + lrow;
            if (n < OC_) {
                float bias = b_off[n];
                #pragma unroll
                for (int r = 0; r < 4; ++r) {
                    int row = wr * 32 + mi * 16 + quad * 4 + r;
                    offbT[(size_t)(M0 + row) * 384 + n] = f2bf(acc[mi][ni][r] + bias);
                }
            }
        }
    }
}

// ---------------------------------------------------------------------------
// Deformable depthwise sample, two-phase.
// Phase 1: per (voxel, tap) geometry computed ONCE -> 24B in LDS.
// Phase 2: thread=(v,c); 3 broadcast LDS dwords + 8 coalesced gathers + FMAs.
// ---------------------------------------------------------------------------
#define VB 8
__global__ __launch_bounds__(256) void deform_kernel(
    const unsigned short* __restrict__ xtb,
    const float* __restrict__ wdwT,
    const float* __restrict__ b_dw,
    const unsigned short* __restrict__ offbT,
    float* __restrict__ attn1T)
{
    __shared__ unsigned short sw[VB * 128 * 12];   // 24 KB
    const int tid = threadIdx.x;
    const int Vb = blockIdx.x * VB;

    for (int idx = tid; idx < VB * 128; idx += 256) {
        int vl = idx >> 7, tap = idx & 127;
        if (tap < K3_) {
            int v = Vb + vl;
            int z = v / 400, rm = v % 400;
            int y = rm / 20, xx = rm % 20;
            int kz = tap / 25, ky = (tap / 5) % 5, kx = tap % 5;
            const unsigned short* ob = offbT + v * 384 + 3 * tap;
            float pd = (float)(z - 2 + kz) + bf2f(ob[0]);
            float ph = (float)(y - 2 + ky) + bf2f(ob[1]);
            float pw = (float)(xx - 2 + kx) + bf2f(ob[2]);
            float fd0 = floorf(pd), fh0 = floorf(ph), fw0 = floorf(pw);
            float fd = pd - fd0, fh = ph - fh0, fw = pw - fw0;
            int id = (int)fd0, ih = (int)fh0, iw = (int)fw0;
            int d0 = min(max(id, 0), S_ - 1), d1 = min(max(id + 1, 0), S_ - 1);
            int h0 = min(max(ih, 0), S_ - 1), h1 = min(max(ih + 1, 0), S_ - 1);
            int w0 = min(max(iw, 0), S_ - 1), w1 = min(max(iw + 1, 0), S_ - 1);
            float wd0 = ((unsigned)id       < (unsigned)S_) ? 1.f - fd : 0.f;
            float wd1 = ((unsigned)(id + 1) < (unsigned)S_) ? fd       : 0.f;
            float wh0 = ((unsigned)ih       < (unsigned)S_) ? 1.f - fh : 0.f;
            float wh1 = ((unsigned)(ih + 1) < (unsigned)S_) ? fh       : 0.f;
            float ww0 = ((unsigned)iw       < (unsigned)S_) ? 1.f - fw : 0.f;
            float ww1 = ((unsigned)(iw + 1) < (unsigned)S_) ? fw       : 0.f;
            unsigned short* p = &sw[idx * 12];
            p[0] = f2bf(wd0 * wh0); p[1] = f2bf(wd0 * wh1);
            p[2] = f2bf(wd1 * wh0); p[3] = f2bf(wd1 * wh1);
            p[4] = f2bf(ww0);       p[5] = f2bf(ww1);
            p[6] = (unsigned short)(d0 * 400 + h0 * 20);
            p[7] = (unsigned short)(d0 * 400 + h1 * 20);
            p[8] = (unsigned short)(d1 * 400 + h0 * 20);
            p[9] = (unsigned short)(d1 * 400 + h1 * 20);
            p[10] = (unsigned short)w0; p[11] = (unsigned short)w1;
        }
    }
    __syncthreads();

    const int c = tid & 31;
    const int vl = tid >> 5;
    const int v = Vb + vl;
    const unsigned short* xc = xtb + c;
    float acc = 0.f;
    #pragma unroll 2
    for (int tap = 0; tap < K3_; ++tap) {
        const unsigned* pu = (const unsigned*)&sw[(vl * 128 + tap) * 12];
        unsigned u0 = pu[0], u1 = pu[1], u2 = pu[2];
        unsigned u3 = pu[3], u4 = pu[4], u5 = pu[5];
        float wdh00 = asf(u0 << 16), wdh01 = asf(u0 & 0xFFFF0000u);
        float wdh10 = asf(u1 << 16), wdh11 = asf(u1 & 0xFFFF0000u);
        float ww0   = asf(u2 << 16), ww1   = asf(u2 & 0xFFFF0000u);
        int r00 = u3 & 0xFFFFu, r01 = u3 >> 16;
        int r10 = u4 & 0xFFFFu, r11 = u4 >> 16;
        int w0  = u5 & 0xFFFFu, w1  = u5 >> 16;
        float x000 = bf2f(xc[(r00 + w0) * 32]);
        float x001 = bf2f(xc[(r00 + w1) * 32]);
        float x010 = bf2f(xc[(r01 + w0) * 32]);
        float x011 = bf2f(xc[(r01 + w1) * 32]);
        float x100 = bf2f(xc[(r10 + w0) * 32]);
        float x101 = bf2f(xc[(r10 + w1) * 32]);
        float x110 = bf2f(xc[(r11 + w0) * 32]);
        float x111 = bf2f(xc[(r11 + w1) * 32]);
        float s = (x000 * ww0 + x001 * ww1) * wdh00
                + (x010 * ww0 + x011 * ww1) * wdh01
                + (x100 * ww0 + x101 * ww1) * wdh10
                + (x110 * ww0 + x111 * ww1) * wdh11;
        acc += wdwT[tap * 32 + c] * s;
    }
    attn1T[v * 32 + c] = acc + b_dw[c];
}

// ---------------------------------------------------------------------------
// Depthwise 7^3 conv, dilation 3, pad 9, channel-last, coalesced.
// ---------------------------------------------------------------------------
__global__ __launch_bounds__(256) void spatial_kernel(
    const float* __restrict__ wspT,
    const float* __restrict__ b_sp,
    const float* __restrict__ attn1T,
    float* __restrict__ attn2T)
{
    int t = threadIdx.x;
    int c = t & 31;
    int v = blockIdx.x * 8 + (t >> 5);
    int z = v / 400, rm = v % 400;
    int y = rm / 20, xx = rm % 20;

    float acc = 0.f;
    #pragma unroll 1
    for (int kz = 0; kz < 7; ++kz) {
        int zi = z - 9 + 3 * kz;
        bool zv = (unsigned)zi < (unsigned)S_;
        int zc2 = min(max(zi, 0), S_ - 1);
        #pragma unroll 1
        for (int ky = 0; ky < 7; ++ky) {
            int yi = y - 9 + 3 * ky;
            bool yv = (unsigned)yi < (unsigned)S_;
            int yc2 = min(max(yi, 0), S_ - 1);
            int abase = (zc2 * 400 + yc2 * 20) * 32 + c;
            int wbase = (kz * 49 + ky * 7) * 32 + c;
            #pragma unroll
            for (int kx = 0; kx < 7; ++kx) {
                int xi = xx - 9 + 3 * kx;
                bool xv = (unsigned)xi < (unsigned)S_;
                int xc2 = min(max(xi, 0), S_ - 1);
                float a = attn1T[abase + xc2 * 32];
                float w = wspT[wbase + kx * 32];
                acc += (zv && yv && xv) ? a * w : 0.f;
            }
        }
    }
    attn2T[v * 32 + c] = acc + b_sp[c];
}

// ---------------------------------------------------------------------------
// Pointwise 32x32 + bias, gate: out[o][v] = x[o][v] * attn.
// ---------------------------------------------------------------------------
__global__ __launch_bounds__(256) void pw_kernel(
    const float* __restrict__ x,
    const float* __restrict__ wpwT,
    const float* __restrict__ b_pw,
    const float* __restrict__ attn2T,
    float* __restrict__ out)
{
    int t = threadIdx.x;
    int o = t & 31;
    int v = blockIdx.x * 8 + (t >> 5);
    float acc = b_pw[o];
    #pragma unroll
    for (int c = 0; c < C_; ++c)
        acc += wpwT[c * 32 + o] * attn2T[v * 32 + c];
    out[o * V_ + v] = x[o * V_ + v] * acc;
}

// ---------------------------------------------------------------------------
extern "C" void kernel_launch(void* const* d_in, const int* in_sizes, int n_in,
                              void* d_out, int out_size, void* d_ws, size_t ws_size,
                              hipStream_t stream)
{
    const float* x     = (const float*)d_in[0];
    const float* w_off = (const float*)d_in[1];
    const float* b_off = (const float*)d_in[2];
    const float* w_dw  = (const float*)d_in[3];
    const float* b_dw  = (const float*)d_in[4];
    const float* w_sp  = (const float*)d_in[5];
    const float* b_sp  = (const float*)d_in[6];
    const float* w_pw  = (const float*)d_in[7];
    const float* b_pw  = (const float*)d_in[8];
    float* ws = (float*)d_ws;
    float* out = (float*)d_out;

    unsigned short* xtb   = (unsigned short*)(ws + WS_XTB);
    unsigned short* offbT = (unsigned short*)(ws + WS_OFFB);
    unsigned short* B2    = (unsigned short*)(ws + WS_BPREP);

    hipLaunchKernelGGL(transpose_kernel, dim3((272032 + 255) / 256), dim3(256), 0, stream,
                       x, w_dw, w_sp, w_pw, xtb,
                       ws + WS_WDWT, ws + WS_WSPT, ws + WS_WPWT);

    hipLaunchKernelGGL(prep_b_kernel, dim3((K3_ * NP_ * C_ + 255) / 256), dim3(256), 0, stream,
                       w_off, B2);

    hipLaunchKernelGGL(gemm_off_kernel, dim3(125, 6), dim3(256), 0, stream,
                       xtb, B2, b_off, offbT);

    hipLaunchKernelGGL(deform_kernel, dim3(1000), dim3(256), 0, stream,
                       xtb, ws + WS_WDWT, b_dw, offbT, ws + WS_ATTN1T);

    hipLaunchKernelGGL(spatial_kernel, dim3(1000), dim3(256), 0, stream,
                       ws + WS_WSPT, b_sp, ws + WS_ATTN1T, ws + WS_ATTN2T);

    hipLaunchKernelGGL(pw_kernel, dim3(1000), dim3(256), 0, stream,
                       x, ws + WS_WPWT, b_pw, ws + WS_ATTN2T, out);
}

// Round 9
// 233.267 us; speedup vs baseline: 1.0965x; 1.0116x over previous
//
#include <hip/hip_runtime.h>
#include <hip/hip_bf16.h>

// Problem constants
#define C_   32
#define S_   20
#define V_   8000     // 20^3
#define K3_  125
#define OC_  375      // 3*K3
#define NP_  384      // padded N
#define KK_  4000     // 32*125
#define PS   24       // padded spatial
#define PS2  576
#define PV   13824    // 24^3

// Workspace layout (float offsets). Peak 2.797M floats = 11.19 MB.
#define WS_ATTN1T 0                        // fp32 [v][c]           256000
#define WS_XPAD   256000                   // bf16 [24][24][24][32] 221184 fl
#define WS_WDWT   477184                   // fp32 [k][c]             4000
#define WS_WSPT   481184                   // fp32 [k][c]            10976
#define WS_WPWT   492160                   // fp32 [c][o]             1024
#define WS_OFFB   493184                   // bf16 [v][384]        1536000 fl
#define WS_BPREP  2029184                  // bf16 [tap][4][384][8] 768000 fl
#define WS_ATTN2T 2029184                  //   dead after gemm -> fp32 [v][c]

typedef __attribute__((ext_vector_type(8))) short bf16x8;
typedef __attribute__((ext_vector_type(4))) float f32x4;

static __device__ __forceinline__ unsigned short f2bf(float f) {
    union { float f; unsigned u; } v; v.f = f;
    unsigned r = v.u + 0x7FFFu + ((v.u >> 16) & 1u);   // RTNE
    return (unsigned short)(r >> 16);
}
static __device__ __forceinline__ float bf2f(unsigned short b) {
    union { unsigned u; float f; } v; v.u = ((unsigned)b) << 16; return v.f;
}
static __device__ __forceinline__ float asf(unsigned u) {
    union { unsigned u; float f; } v; v.u = u; return v.f;
}

// ---------------------------------------------------------------------------
// Prep: zero-padded channel-last xpad[pz][py][px][c] bf16; weight transposes.
// ---------------------------------------------------------------------------
__global__ __launch_bounds__(256) void transpose_kernel(
    const float* __restrict__ x,
    const float* __restrict__ w_dw,
    const float* __restrict__ w_sp,
    const float* __restrict__ w_pw,
    unsigned short* __restrict__ xpad,
    float* __restrict__ wdwT,
    float* __restrict__ wspT,
    float* __restrict__ wpwT)
{
    int i = blockIdx.x * 256 + threadIdx.x;
    if (i < PV * C_) {
        int vp = i >> 5, c = i & 31;
        int pz = vp / PS2, rm = vp % PS2;
        int py = rm / PS, px = rm % PS;
        int z = pz - 2, y = py - 2, xx = px - 2;
        unsigned short val = 0;
        if ((unsigned)z < (unsigned)S_ && (unsigned)y < (unsigned)S_ &&
            (unsigned)xx < (unsigned)S_)
            val = f2bf(x[c * V_ + z * 400 + y * 20 + xx]);
        xpad[i] = val;
        return;
    }
    int j = i - PV * C_;
    if (j < 4000)  { wdwT[j] = w_dw[(j & 31) * K3_ + (j >> 5)]; return; }
    j -= 4000;
    if (j < 10976) { wspT[j] = w_sp[(j & 31) * 343 + (j >> 5)]; return; }
    j -= 10976;
    if (j < 1024)  { wpwT[j] = w_pw[(j & 31) * 32 + (j >> 5)]; return; }
}

// ---------------------------------------------------------------------------
// Weight transform: B2[tap][q][n][8] bf16 (n >= 375 zeroed), element =
// w_off[n][c=q*8+j][tap]. Every gemm B-fragment load is contiguous.
// ---------------------------------------------------------------------------
__global__ __launch_bounds__(256) void prep_b_kernel(
    const float* __restrict__ w_off, unsigned short* __restrict__ B2)
{
    int idx = blockIdx.x * 256 + threadIdx.x;
    if (idx >= K3_ * NP_ * C_) return;
    int tap = idx / 12288;
    int r   = idx % 12288;
    int q  = r / 3072;
    int r2 = r % 3072;
    int n = r2 >> 3, j = r2 & 7;
    int c = q * 8 + j;
    float v = (n < OC_) ? w_off[n * KK_ + c * K3_ + tap] : 0.f;
    B2[idx] = f2bf(v);
}

// ---------------------------------------------------------------------------
// Offset conv as implicit-GEMM MFMA: D[8000][384] = A[8000][4000]*B[4000][384].
// Barrier/LDS-free. A addresses from padded volume: per-lane base + wave-
// uniform tap offset (SALU) — no masks/clamps. 6-tap rotating register
// prefetch (24 loads in flight). Tile 64x64, 4 waves 2x2, wave tile 32x32.
// ---------------------------------------------------------------------------
#define PF 6
__global__ __launch_bounds__(256, 3) void gemm_off_kernel(
    const unsigned short* __restrict__ xpad,
    const unsigned short* __restrict__ B2,
    const float* __restrict__ b_off,
    unsigned short* __restrict__ offbT)
{
    const int t    = threadIdx.x;
    const int lane = t & 63;
    const int wave = t >> 6;
    const int wr   = wave >> 1;
    const int wc   = wave & 1;
    const int quad = lane >> 4;
    const int lrow = lane & 15;
    const int M0   = blockIdx.x * 64;
    const int N0   = blockIdx.y * 64;

    const int m0 = M0 + wr * 32 + lrow;
    const int m1 = m0 + 16;
    const int az0 = m0 / 400, rr0 = m0 % 400, ay0 = rr0 / 20, ax0 = rr0 % 20;
    const int az1 = m1 / 400, rr1 = m1 % 400, ay1 = rr1 / 20, ax1 = rr1 % 20;
    // padded-base element index (voxel (z,y,x) at tap k -> base + tapoff)
    const unsigned short* ap0 = xpad + (az0 * PS2 + ay0 * PS + ax0) * 32 + quad * 8;
    const unsigned short* ap1 = xpad + (az1 * PS2 + ay1 * PS + ax1) * 32 + quad * 8;

    const unsigned short* bp0 = B2 + ((size_t)quad * NP_ + (N0 + wc * 32 + lrow)) * 8;
    const unsigned short* bp1 = bp0 + 16 * 8;

    bf16x8 a0b[PF], a1b[PF], b0b[PF], b1b[PF];

    auto loadtap = [&](int tap, int slot) {
        int tc = min(tap, K3_ - 1);
        int kz = tc / 25, r = tc % 25, ky = r / 5, kx = r % 5;
        int toff = (kz * PS2 + ky * PS + kx) * 32;     // wave-uniform (SALU)
        a0b[slot] = *(const bf16x8*)(ap0 + toff);
        a1b[slot] = *(const bf16x8*)(ap1 + toff);
        b0b[slot] = *(const bf16x8*)(bp0 + (size_t)tc * 12288);
        b1b[slot] = *(const bf16x8*)(bp1 + (size_t)tc * 12288);
    };

    #pragma unroll
    for (int s = 0; s < PF; ++s) loadtap(s, s);

    f32x4 acc[2][2] = {};
    #pragma unroll 1
    for (int tb = 0; tb < 120; tb += PF) {
        #pragma unroll
        for (int u = 0; u < PF; ++u) {
            bf16x8 ca0 = a0b[u], ca1 = a1b[u], cb0 = b0b[u], cb1 = b1b[u];
            loadtap(tb + PF + u, u);
            acc[0][0] = __builtin_amdgcn_mfma_f32_16x16x32_bf16(ca0, cb0, acc[0][0], 0, 0, 0);
            acc[0][1] = __builtin_amdgcn_mfma_f32_16x16x32_bf16(ca0, cb1, acc[0][1], 0, 0, 0);
            acc[1][0] = __builtin_amdgcn_mfma_f32_16x16x32_bf16(ca1, cb0, acc[1][0], 0, 0, 0);
            acc[1][1] = __builtin_amdgcn_mfma_f32_16x16x32_bf16(ca1, cb1, acc[1][1], 0, 0, 0);
        }
    }
    #pragma unroll
    for (int u = 0; u < 5; ++u) {   // taps 120..124 sit in slots 0..4
        bf16x8 ca0 = a0b[u], ca1 = a1b[u], cb0 = b0b[u], cb1 = b1b[u];
        acc[0][0] = __builtin_amdgcn_mfma_f32_16x16x32_bf16(ca0, cb0, acc[0][0], 0, 0, 0);
        acc[0][1] = __builtin_amdgcn_mfma_f32_16x16x32_bf16(ca0, cb1, acc[0][1], 0, 0, 0);
        acc[1][0] = __builtin_amdgcn_mfma_f32_16x16x32_bf16(ca1, cb0, acc[1][0], 0, 0, 0);
        acc[1][1] = __builtin_amdgcn_mfma_f32_16x16x32_bf16(ca1, cb1, acc[1][1], 0, 0, 0);
    }

    #pragma unroll
    for (int mi = 0; mi < 2; ++mi) {
        #pragma unroll
        for (int ni = 0; ni < 2; ++ni) {
            int n = N0 + wc * 32 + ni * 16 + lrow;
            if (n < OC_) {
                float bias = b_off[n];
                #pragma unroll
                for (int r = 0; r < 4; ++r) {
                    int row = wr * 32 + mi * 16 + quad * 4 + r;
                    offbT[(size_t)(M0 + row) * 384 + n] = f2bf(acc[mi][ni][r] + bias);
                }
            }
        }
    }
}

// ---------------------------------------------------------------------------
// Deformable depthwise sample, two-phase (gathers from padded volume).
// Phase 1: per (voxel, tap) geometry computed ONCE -> 24B in LDS.
// Phase 2: thread=(v,c); 3 broadcast LDS dwords + 8 coalesced gathers + FMAs.
// ---------------------------------------------------------------------------
#define VB 8
__global__ __launch_bounds__(256) void deform_kernel(
    const unsigned short* __restrict__ xpad,
    const float* __restrict__ wdwT,
    const float* __restrict__ b_dw,
    const unsigned short* __restrict__ offbT,
    float* __restrict__ attn1T)
{
    __shared__ unsigned short sw[VB * 128 * 12];   // 24 KB
    const int tid = threadIdx.x;
    const int Vb = blockIdx.x * VB;

    for (int idx = tid; idx < VB * 128; idx += 256) {
        int vl = idx >> 7, tap = idx & 127;
        if (tap < K3_) {
            int v = Vb + vl;
            int z = v / 400, rm = v % 400;
            int y = rm / 20, xx = rm % 20;
            int kz = tap / 25, ky = (tap / 5) % 5, kx = tap % 5;
            const unsigned short* ob = offbT + v * 384 + 3 * tap;
            float pd = (float)(z - 2 + kz) + bf2f(ob[0]);
            float ph = (float)(y - 2 + ky) + bf2f(ob[1]);
            float pw = (float)(xx - 2 + kx) + bf2f(ob[2]);
            float fd0 = floorf(pd), fh0 = floorf(ph), fw0 = floorf(pw);
            float fd = pd - fd0, fh = ph - fh0, fw = pw - fw0;
            int id = (int)fd0, ih = (int)fh0, iw = (int)fw0;
            int d0 = min(max(id, 0), S_ - 1), d1 = min(max(id + 1, 0), S_ - 1);
            int h0 = min(max(ih, 0), S_ - 1), h1 = min(max(ih + 1, 0), S_ - 1);
            int w0 = min(max(iw, 0), S_ - 1), w1 = min(max(iw + 1, 0), S_ - 1);
            float wd0 = ((unsigned)id       < (unsigned)S_) ? 1.f - fd : 0.f;
            float wd1 = ((unsigned)(id + 1) < (unsigned)S_) ? fd       : 0.f;
            float wh0 = ((unsigned)ih       < (unsigned)S_) ? 1.f - fh : 0.f;
            float wh1 = ((unsigned)(ih + 1) < (unsigned)S_) ? fh       : 0.f;
            float ww0 = ((unsigned)iw       < (unsigned)S_) ? 1.f - fw : 0.f;
            float ww1 = ((unsigned)(iw + 1) < (unsigned)S_) ? fw       : 0.f;
            unsigned short* p = &sw[idx * 12];
            p[0] = f2bf(wd0 * wh0); p[1] = f2bf(wd0 * wh1);
            p[2] = f2bf(wd1 * wh0); p[3] = f2bf(wd1 * wh1);
            p[4] = f2bf(ww0);       p[5] = f2bf(ww1);
            // padded row bases: coord+2, +2 for w folded in
            p[6] = (unsigned short)((d0 + 2) * PS2 + (h0 + 2) * PS + 2);
            p[7] = (unsigned short)((d0 + 2) * PS2 + (h1 + 2) * PS + 2);
            p[8] = (unsigned short)((d1 + 2) * PS2 + (h0 + 2) * PS + 2);
            p[9] = (unsigned short)((d1 + 2) * PS2 + (h1 + 2) * PS + 2);
            p[10] = (unsigned short)w0; p[11] = (unsigned short)w1;
        }
    }
    __syncthreads();

    const int c = tid & 31;
    const int vl = tid >> 5;
    const int v = Vb + vl;
    const unsigned short* xc = xpad + c;
    float acc = 0.f;
    #pragma unroll 2
    for (int tap = 0; tap < K3_; ++tap) {
        const unsigned* pu = (const unsigned*)&sw[(vl * 128 + tap) * 12];
        unsigned u0 = pu[0], u1 = pu[1], u2 = pu[2];
        unsigned u3 = pu[3], u4 = pu[4], u5 = pu[5];
        float wdh00 = asf(u0 << 16), wdh01 = asf(u0 & 0xFFFF0000u);
        float wdh10 = asf(u1 << 16), wdh11 = asf(u1 & 0xFFFF0000u);
        float ww0   = asf(u2 << 16), ww1   = asf(u2 & 0xFFFF0000u);
        int r00 = u3 & 0xFFFFu, r01 = u3 >> 16;
        int r10 = u4 & 0xFFFFu, r11 = u4 >> 16;
        int w0  = u5 & 0xFFFFu, w1  = u5 >> 16;
        float x000 = bf2f(xc[(r00 + w0) * 32]);
        float x001 = bf2f(xc[(r00 + w1) * 32]);
        float x010 = bf2f(xc[(r01 + w0) * 32]);
        float x011 = bf2f(xc[(r01 + w1) * 32]);
        float x100 = bf2f(xc[(r10 + w0) * 32]);
        float x101 = bf2f(xc[(r10 + w1) * 32]);
        float x110 = bf2f(xc[(r11 + w0) * 32]);
        float x111 = bf2f(xc[(r11 + w1) * 32]);
        float s = (x000 * ww0 + x001 * ww1) * wdh00
                + (x010 * ww0 + x011 * ww1) * wdh01
                + (x100 * ww0 + x101 * ww1) * wdh10
                + (x110 * ww0 + x111 * ww1) * wdh11;
        acc += wdwT[tap * 32 + c] * s;
    }
    attn1T[v * 32 + c] = acc + b_dw[c];
}

// ---------------------------------------------------------------------------
// Depthwise 7^3 conv, dilation 3, pad 9, channel-last, coalesced.
// ---------------------------------------------------------------------------
__global__ __launch_bounds__(256) void spatial_kernel(
    const float* __restrict__ wspT,
    const float* __restrict__ b_sp,
    const float* __restrict__ attn1T,
    float* __restrict__ attn2T)
{
    int t = threadIdx.x;
    int c = t & 31;
    int v = blockIdx.x * 8 + (t >> 5);
    int z = v / 400, rm = v % 400;
    int y = rm / 20, xx = rm % 20;

    float acc = 0.f;
    #pragma unroll 1
    for (int kz = 0; kz < 7; ++kz) {
        int zi = z - 9 + 3 * kz;
        bool zv = (unsigned)zi < (unsigned)S_;
        int zc2 = min(max(zi, 0), S_ - 1);
        #pragma unroll 1
        for (int ky = 0; ky < 7; ++ky) {
            int yi = y - 9 + 3 * ky;
            bool yv = (unsigned)yi < (unsigned)S_;
            int yc2 = min(max(yi, 0), S_ - 1);
            int abase = (zc2 * 400 + yc2 * 20) * 32 + c;
            int wbase = (kz * 49 + ky * 7) * 32 + c;
            #pragma unroll
            for (int kx = 0; kx < 7; ++kx) {
                int xi = xx - 9 + 3 * kx;
                bool xv = (unsigned)xi < (unsigned)S_;
                int xc2 = min(max(xi, 0), S_ - 1);
                float a = attn1T[abase + xc2 * 32];
                float w = wspT[wbase + kx * 32];
                acc += (zv && yv && xv) ? a * w : 0.f;
            }
        }
    }
    attn2T[v * 32 + c] = acc + b_sp[c];
}

// ---------------------------------------------------------------------------
// Pointwise 32x32 + bias, gate: out[o][v] = x[o][v] * attn.
// ---------------------------------------------------------------------------
__global__ __launch_bounds__(256) void pw_kernel(
    const float* __restrict__ x,
    const float* __restrict__ wpwT,
    const float* __restrict__ b_pw,
    const float* __restrict__ attn2T,
    float* __restrict__ out)
{
    int t = threadIdx.x;
    int o = t & 31;
    int v = blockIdx.x * 8 + (t >> 5);
    float acc = b_pw[o];
    #pragma unroll
    for (int c = 0; c < C_; ++c)
        acc += wpwT[c * 32 + o] * attn2T[v * 32 + c];
    out[o * V_ + v] = x[o * V_ + v] * acc;
}

// ---------------------------------------------------------------------------
extern "C" void kernel_launch(void* const* d_in, const int* in_sizes, int n_in,
                              void* d_out, int out_size, void* d_ws, size_t ws_size,
                              hipStream_t stream)
{
    const float* x     = (const float*)d_in[0];
    const float* w_off = (const float*)d_in[1];
    const float* b_off = (const float*)d_in[2];
    const float* w_dw  = (const float*)d_in[3];
    const float* b_dw  = (const float*)d_in[4];
    const float* w_sp  = (const float*)d_in[5];
    const float* b_sp  = (const float*)d_in[6];
    const float* w_pw  = (const float*)d_in[7];
    const float* b_pw  = (const float*)d_in[8];
    float* ws = (float*)d_ws;
    float* out = (float*)d_out;

    unsigned short* xpad  = (unsigned short*)(ws + WS_XPAD);
    unsigned short* offbT = (unsigned short*)(ws + WS_OFFB);
    unsigned short* B2    = (unsigned short*)(ws + WS_BPREP);

    const int n_t = PV * C_ + 16000;
    hipLaunchKernelGGL(transpose_kernel, dim3((n_t + 255) / 256), dim3(256), 0, stream,
                       x, w_dw, w_sp, w_pw, xpad,
                       ws + WS_WDWT, ws + WS_WSPT, ws + WS_WPWT);

    hipLaunchKernelGGL(prep_b_kernel, dim3((K3_ * NP_ * C_ + 255) / 256), dim3(256), 0, stream,
                       w_off, B2);

    hipLaunchKernelGGL(gemm_off_kernel, dim3(125, 6), dim3(256), 0, stream,
                       xpad, B2, b_off, offbT);

    hipLaunchKernelGGL(deform_kernel, dim3(1000), dim3(256), 0, stream,
                       xpad, ws + WS_WDWT, b_dw, offbT, ws + WS_ATTN1T);

    hipLaunchKernelGGL(spatial_kernel, dim3(1000), dim3(256), 0, stream,
                       ws + WS_WSPT, b_sp, ws + WS_ATTN1T, ws + WS_ATTN2T);

    hipLaunchKernelGGL(pw_kernel, dim3(1000), dim3(256), 0, stream,
                       x, ws + WS_WPWT, b_pw, ws + WS_ATTN2T, out);
}